// Round 2
// baseline (83350.366 us; speedup 1.0000x reference)
//
#include <hip/hip_runtime.h>
#include <cmath>

#define NN 1024
#define DD 1024
#define BB 8
#define LL 4
#define OUTD (DD*(LL+1))   // 5120
#define NB 32
#define NPAN (NN/NB)       // 32
#define CS 32
#define BSTR ((size_t)NN*OUTD)

// ---------------- setup kernels ----------------
__global__ void k_deg_init(float* degF){ degF[threadIdx.x]=0.f; }

__global__ void k_deg(const int* __restrict__ ei, float* __restrict__ degF, int E){
  int e=blockIdx.x*blockDim.x+threadIdx.x;
  if(e<E) atomicAdd(&degF[ei[2*e]],1.f);
}

__global__ void k_scan(const float* __restrict__ degF, float* __restrict__ isq, int* __restrict__ rowoff){
  __shared__ int s[NN];
  int i=threadIdx.x;
  int d=(int)degF[i];
  s[i]=d; __syncthreads();
  for(int off=1;off<NN;off<<=1){
    int v=(i>=off)?s[i-off]:0;
    __syncthreads();
    s[i]+=v;
    __syncthreads();
  }
  if(i==0) rowoff[0]=0;
  rowoff[i+1]=s[i];
  isq[i]=(d>0)?(float)(1.0/sqrt((double)d)):0.f;
}

__global__ void k_copyx0(const float* __restrict__ x0, float* __restrict__ out){
  size_t t=(size_t)blockIdx.x*blockDim.x+threadIdx.x;
  if(t>=(size_t)BB*NN*DD) return;
  int d=(int)(t&(DD-1)); size_t bn=t>>10;
  out[bn*OUTD+d]=x0[t];
}

// ---------------- graph conv (writes A into out slab, ld=OUTD) -------------
__global__ void k_conv(const float* __restrict__ xin, const int* __restrict__ ei,
                       const float* __restrict__ degF, const float* __restrict__ isq,
                       const int* __restrict__ rowoff, float* Aout){
  int i=blockIdx.x, b=blockIdx.y;
  __shared__ int sdst[64]; __shared__ float sw[64];
  int r0=rowoff[i], r1=rowoff[i+1];
  int cnt=r1-r0; if(cnt>64) cnt=64;
  float di=degF[i], isqi=isq[i];
  for(int e=threadIdx.x;e<cnt;e+=blockDim.x){
    int dv=ei[2*(r0+e)+1];
    sdst[e]=dv; sw[e]=isqi*isq[dv];
  }
  __syncthreads();
  float cm=((float)(r1-r0))*di/fmaxf(di,1.f);
  const float* xi=xin+((size_t)(b*NN+i))*OUTD;
  float* ao=Aout+((size_t)(b*NN+i))*OUTD;
  for(int d=threadIdx.x; d<DD; d+=blockDim.x){
    float acc=0.f;
    for(int e=0;e<cnt;e++) acc+=sw[e]*xin[((size_t)(b*NN+sdst[e]))*OUTD+d];
    ao[d]=0.5f*acc+0.5f*cm*xi[d];
  }
}

// ---------------- Householder panel (LAPACK slarfg convention) -------------
// Factors A[k0:N, k0:k0+32] in LDS. Writes back: strict-lower = V (unit diag
// implicit); upper-incl-diag of the 32x32 diagonal block = packed compact-WY T
// (R is dead — we only ever output Q). Rows of R above are left stale; they
// are deterministically zeroed by k_form before any later read.
__global__ __launch_bounds__(256) void k_panel(float* A, int k0){
  int b=blockIdx.x;
  int m=NN-k0;
  extern __shared__ float sm[];
  float* P   = sm;                 // m*33 (pad to 33)
  float* red = P+(size_t)m*33;     // 256
  float* w   = red+256;            // 32
  float* taus= w+32;               // 32
  float* dots= taus+32;            // 32
  float* Tsh = dots+32;            // 32*32
  float* scal= Tsh+NB*NB;          // 4
  float* Ab=A+(size_t)b*BSTR;
  int tid=threadIdx.x;

  for(int idx=tid; idx<m*NB; idx+=256){
    int r=idx>>5, j=idx&31;
    P[r*33+j]=Ab[(size_t)(k0+r)*OUTD+k0+j];
  }
  for(int idx=tid; idx<NB*NB; idx+=256) Tsh[idx]=0.f;
  __syncthreads();

  int col=tid&31, rg=tid>>5;
  for(int j=0;j<NB;j++){
    float ss=0.f;
    for(int r=j+1+tid;r<m;r+=256){ float v=P[r*33+j]; ss+=v*v; }
    red[tid]=ss; __syncthreads();
    for(int o=128;o>0;o>>=1){ if(tid<o) red[tid]+=red[tid+o]; __syncthreads(); }
    if(tid==0){
      float alpha=P[j*33+j], ssq=red[0];
      float tau,beta,scale;
      if(ssq==0.f){ tau=0.f; beta=alpha; scale=0.f; }
      else{
        double bn=sqrt((double)alpha*(double)alpha+(double)ssq);
        beta=(alpha>=0.f)?(float)(-bn):(float)bn;   // beta = -sign(alpha)*norm
        tau=(beta-alpha)/beta;
        scale=1.f/(alpha-beta);
      }
      taus[j]=tau; scal[0]=scale; P[j*33+j]=beta;
    }
    __syncthreads();
    float tau=taus[j], scale=scal[0];
    for(int r=j+1+tid;r<m;r+=256) P[r*33+j]*=scale;
    __syncthreads();
    float acc=0.f;
    if(col>j){ for(int r=j+1+rg;r<m;r+=8) acc+=P[r*33+j]*P[r*33+col]; }
    red[rg*32+col]=acc; __syncthreads();
    if(tid<NB && tid>j){
      float s2=P[j*33+tid];
      for(int g=0;g<8;g++) s2+=red[g*32+tid];
      w[tid]=tau*s2;
    }
    __syncthreads();
    if(col>j){
      float wc=w[col];
      for(int r=j+rg;r<m;r+=8){
        float v=(r==j)?1.f:P[r*33+j];
        P[r*33+col]-=wc*v;
      }
    }
    __syncthreads();
  }

  // compact-WY T (larft forward): T(0:j-1,j) = -tau_j * T * (V^T v_j)
  for(int j=0;j<NB;j++){
    float acc=0.f;
    if(col<j){ for(int r=j+1+rg;r<m;r+=8) acc+=P[r*33+col]*P[r*33+j]; }
    red[rg*32+col]=acc; __syncthreads();
    if(tid<j){
      float s2=P[j*33+tid];
      for(int g=0;g<8;g++) s2+=red[g*32+tid];
      dots[tid]=s2;
    }
    __syncthreads();
    if(tid<j){
      float s=0.f;
      for(int q=tid;q<j;q++) s+=Tsh[tid*NB+q]*dots[q];
      Tsh[tid*NB+j]=-taus[j]*s;
    }
    if(tid==j) Tsh[j*NB+j]=taus[j];
    __syncthreads();
  }

  // writeback: V strict-lower; packed T on upper-incl-diag of diag block
  for(int idx=tid; idx<m*NB; idx+=256){
    int r=idx>>5, j=idx&31;
    float v=(r>j)?P[r*33+j]:Tsh[r*NB+j];
    Ab[(size_t)(k0+r)*OUTD+k0+j]=v;
  }
}

// ---------------- block reflector apply (larfb) ----------------------------
// TRANS_T=true :  cols <- (I - V T^T V^T) cols   (geqrf trailing update)
// TRANS_T=false:  cols <- (I - V T   V^T) cols   (orgqr right-apply)
// V and packed T read from panel kb's columns of the same slab; target is a
// CS-column stripe at c0 >= k0+NB (disjoint from V/T columns).
template<bool TRANS_T>
__global__ __launch_bounds__(256) void k_update(float* A, int col0, int k0){
  int b=blockIdx.y;
  int c0=col0+blockIdx.x*CS;
  int m=NN-k0;
  float* Ab=A+(size_t)b*BSTR;
  __shared__ float Tsh[NB*NB];
  __shared__ float W[NB][CS+1];
  __shared__ float Vt[64][NB+1];
  __shared__ float Wp[8][NB][CS+1];
  int tid=threadIdx.x;
  int c=tid&(CS-1), rg=tid>>5;
  for(int idx=tid; idx<NB*NB; idx+=256){
    int q=idx>>5, j=idx&31;
    float v=Ab[(size_t)(k0+q)*OUTD+k0+j];
    Tsh[idx]=(q<=j)?v:0.f;
  }
  float acc[NB];
  #pragma unroll
  for(int j=0;j<NB;j++) acc[j]=0.f;
  // pass 1: W = V^T * stripe
  for(int rt=0;rt<m;rt+=64){
    __syncthreads();
    for(int idx=tid; idx<64*NB; idx+=256){
      int rr=idx>>5, j=idx&31; int r=rt+rr; float v=0.f;
      if(r<m) v=(r<j)?0.f:((r==j)?1.f:Ab[(size_t)(k0+r)*OUTD+k0+j]);
      Vt[rr][j]=v;
    }
    __syncthreads();
    for(int rr=rg;rr<64;rr+=8){
      int r=rt+rr;
      if(r<m){
        float a=Ab[(size_t)(k0+r)*OUTD+c0+c];
        #pragma unroll
        for(int j=0;j<NB;j++) acc[j]+=Vt[rr][j]*a;
      }
    }
  }
  __syncthreads();
  #pragma unroll
  for(int j=0;j<NB;j++) Wp[rg][j][c]=acc[j];
  __syncthreads();
  for(int idx=tid; idx<NB*CS; idx+=256){
    int j=idx>>5, cc=idx&31;
    float s=0.f;
    #pragma unroll
    for(int g=0;g<8;g++) s+=Wp[g][j][cc];
    W[j][cc]=s;
  }
  __syncthreads();
  float w2[4];
  #pragma unroll
  for(int k=0;k<4;k++){
    int j=rg+8*k;
    float s=0.f;
    if(TRANS_T){ for(int q=0;q<=j;q++) s+=Tsh[q*NB+j]*W[q][c]; }
    else       { for(int q=j;q<NB;q++) s+=Tsh[j*NB+q]*W[q][c]; }
    w2[k]=s;
  }
  __syncthreads();
  #pragma unroll
  for(int k=0;k<4;k++) W[rg+8*k][c]=w2[k];
  __syncthreads();
  // pass 2: stripe -= V * W
  for(int rt=0;rt<m;rt+=64){
    for(int idx=tid; idx<64*NB; idx+=256){
      int rr=idx>>5, j=idx&31; int r=rt+rr; float v=0.f;
      if(r<m) v=(r<j)?0.f:((r==j)?1.f:Ab[(size_t)(k0+r)*OUTD+k0+j]);
      Vt[rr][j]=v;
    }
    __syncthreads();
    for(int rr=rg;rr<64;rr+=8){
      int r=rt+rr;
      if(r<m){
        float s=0.f;
        #pragma unroll
        for(int j=0;j<NB;j++) s+=Vt[rr][j]*W[j][c];
        Ab[(size_t)(k0+r)*OUTD+c0+c]-=s;
      }
    }
    __syncthreads();
  }
}

// ---------------- form panel's own Q columns in place -----------------------
// cols[k0:k0+32] <- E - V*(T*Vtop^T), rows [k0,N); rows [0,k0) <- 0.
// One block per batch; internal load-then-overwrite ordering is sync-safe.
__global__ __launch_bounds__(256) void k_form(float* A, int k0){
  int b=blockIdx.x;
  int m=NN-k0;
  float* Ab=A+(size_t)b*BSTR;
  __shared__ float Tsh[NB*NB];
  __shared__ float Vtop[NB][NB+1];
  __shared__ float S[NB][NB+1];
  __shared__ float Vt[64][NB+1];
  int tid=threadIdx.x;
  for(int idx=tid; idx<NB*NB; idx+=256){
    int r=idx>>5, j=idx&31;
    float v=Ab[(size_t)(k0+r)*OUTD+k0+j];
    Tsh[idx]=(r<=j)?v:0.f;                       // packed T (upper)
    Vtop[r][j]=(r<j)?0.f:((r==j)?1.f:v);         // V top 32 rows (unit lower)
  }
  __syncthreads();
  // S = T * Vtop^T : S[q][j] = sum_p T[q][p]*Vtop[j][p]
  for(int idx=tid; idx<NB*NB; idx+=256){
    int q=idx>>5, j=idx&31;
    float s=0.f;
    for(int p=q;p<NB;p++) s+=Tsh[q*NB+p]*Vtop[j][p];
    S[q][j]=s;
  }
  __syncthreads();
  int c=tid&31, rg=tid>>5;
  for(int rt=0;rt<m;rt+=64){
    for(int idx=tid; idx<64*NB; idx+=256){
      int rr=idx>>5, j=idx&31; int r=rt+rr; float v=0.f;
      if(r<m) v=(r<j)?0.f:((r==j)?1.f:Ab[(size_t)(k0+r)*OUTD+k0+j]);
      Vt[rr][j]=v;
    }
    __syncthreads();
    for(int rr=rg;rr<64;rr+=8){
      int r=rt+rr;
      if(r<m){
        float s=0.f;
        #pragma unroll
        for(int q=0;q<NB;q++) s+=Vt[rr][q]*S[q][c];
        Ab[(size_t)(k0+r)*OUTD+k0+c]=((r==c)?1.f:0.f)-s;
      }
    }
    __syncthreads();
  }
  // zero rows [0,k0) of this panel's columns (kills stale R deterministically)
  for(int idx=tid; idx<k0*NB; idx+=256){
    int r=idx>>5, j=idx&31;
    Ab[(size_t)r*OUTD+k0+j]=0.f;
  }
}

extern "C" void kernel_launch(void* const* d_in, const int* in_sizes, int n_in,
                              void* d_out, int out_size, void* d_ws, size_t ws_size,
                              hipStream_t stream){
  const float* x0=(const float*)d_in[0];
  const int* ei=(const int*)d_in[1];
  int E=in_sizes[1]/2;
  float* out=(float*)d_out;
  // ws usage: 12.3 KB total (deg table + inv-sqrt + CSR offsets)
  float* degF=(float*)d_ws;          // N
  float* isq =degF+NN;               // N
  int*  rowoff=(int*)(isq+NN);       // N+1

  (void)hipFuncSetAttribute(reinterpret_cast<const void*>(&k_panel),
                            hipFuncAttributeMaxDynamicSharedMemorySize, 150*1024);

  size_t tot=(size_t)BB*NN*DD;
  k_deg_init<<<1,NN,0,stream>>>(degF);
  k_deg<<<(E+255)/256,256,0,stream>>>(ei,degF,E);
  k_scan<<<1,NN,0,stream>>>(degF,isq,rowoff);
  k_copyx0<<<(int)((tot+255)/256),256,0,stream>>>(x0,out);

  for(int l=0;l<LL;l++){
    float* A = out + (size_t)(l+1)*DD;   // slab l+1 is A/V/T/Q workspace
    k_conv<<<dim3(NN,BB),256,0,stream>>>(out+(size_t)l*DD,ei,degF,isq,rowoff,A);
    // geqrf (blocked, in place)
    for(int kb=0;kb<NPAN;kb++){
      int k0=kb*NB, m=NN-k0;
      size_t smem=((size_t)m*33+1380)*sizeof(float);
      k_panel<<<BB,256,smem,stream>>>(A,k0);
      int nc=NN-k0-NB;
      if(nc>0){
        dim3 g(nc/CS,BB);
        k_update<true><<<g,256,0,stream>>>(A,k0+NB,k0);
      }
    }
    // orgqr (in place, backward): right-apply then form own columns
    for(int kb=NPAN-1;kb>=0;kb--){
      int k0=kb*NB;
      int nc=NN-k0-NB;
      if(nc>0){
        dim3 g(nc/CS,BB);
        k_update<false><<<g,256,0,stream>>>(A,k0+NB,k0);
      }
      k_form<<<BB,256,0,stream>>>(A,k0);
    }
  }
}

// Round 3
// 45943.033 us; speedup vs baseline: 1.8142x; 1.8142x over previous
//
#include <hip/hip_runtime.h>
#include <cmath>

#define NN 1024
#define DD 1024
#define BB 8
#define LL 4
#define OUTD (DD*(LL+1))   // 5120
#define NB 32
#define NPAN (NN/NB)       // 32
#define CS 32
#define BSTR ((size_t)NN*OUTD)

// ---------------- setup kernels ----------------
__global__ void k_deg_init(float* degF){ degF[threadIdx.x]=0.f; }

__global__ void k_deg(const int* __restrict__ ei, float* __restrict__ degF, int E){
  int e=blockIdx.x*blockDim.x+threadIdx.x;
  if(e<E) atomicAdd(&degF[ei[2*e]],1.f);
}

__global__ void k_scan(const float* __restrict__ degF, float* __restrict__ isq, int* __restrict__ rowoff){
  __shared__ int s[NN];
  int i=threadIdx.x;
  int d=(int)degF[i];
  s[i]=d; __syncthreads();
  for(int off=1;off<NN;off<<=1){
    int v=(i>=off)?s[i-off]:0;
    __syncthreads();
    s[i]+=v;
    __syncthreads();
  }
  if(i==0) rowoff[0]=0;
  rowoff[i+1]=s[i];
  isq[i]=(d>0)?(float)(1.0/sqrt((double)d)):0.f;
}

__global__ void k_copyx0(const float* __restrict__ x0, float* __restrict__ out){
  size_t t=(size_t)blockIdx.x*blockDim.x+threadIdx.x;
  if(t>=(size_t)BB*NN*DD) return;
  int d=(int)(t&(DD-1)); size_t bn=t>>10;
  out[bn*OUTD+d]=x0[t];
}

// ---------------- graph conv (writes A into out slab, ld=OUTD) -------------
__global__ void k_conv(const float* __restrict__ xin, const int* __restrict__ ei,
                       const float* __restrict__ degF, const float* __restrict__ isq,
                       const int* __restrict__ rowoff, float* Aout){
  int i=blockIdx.x, b=blockIdx.y;
  __shared__ int sdst[64]; __shared__ float sw[64];
  int r0=rowoff[i], r1=rowoff[i+1];
  int cnt=r1-r0; if(cnt>64) cnt=64;
  float di=degF[i], isqi=isq[i];
  for(int e=threadIdx.x;e<cnt;e+=blockDim.x){
    int dv=ei[2*(r0+e)+1];
    sdst[e]=dv; sw[e]=isqi*isq[dv];
  }
  __syncthreads();
  float cm=((float)(r1-r0))*di/fmaxf(di,1.f);
  const float* xi=xin+((size_t)(b*NN+i))*OUTD;
  float* ao=Aout+((size_t)(b*NN+i))*OUTD;
  for(int d=threadIdx.x; d<DD; d+=blockDim.x){
    float acc=0.f;
    for(int e=0;e<cnt;e++) acc+=sw[e]*xin[((size_t)(b*NN+sdst[e]))*OUTD+d];
    ao[d]=0.5f*acc+0.5f*cm*xi[d];
  }
}

// ---------------- register-resident Householder panel ----------------------
// 1024 threads: thread (c=tid&31, rg=tid>>5) owns P[rg+32q][c] in registers.
// Factors A[k0:N, k0:k0+32]; writes V strict-lower, packed compact-WY T into
// the diag block's upper-incl-diag (R is dead), and dumps explicit Vtop + T
// into ws for the later race-free Q formation.
__global__ __launch_bounds__(1024) void k_panelR(float* A, int k0, float* vtws){
  int b=blockIdx.x;
  int m=NN-k0;
  int mq=m>>5;                      // owned rows per thread (<=32)
  int tid=threadIdx.x;
  int c=tid&31, rg=tid>>5;
  float* Ab=A+(size_t)b*BSTR;
  __shared__ float vsh[NN];         // v_j broadcast (rows [j,m))
  __shared__ float red[32*33];      // [rg][c] partials, pad 33; col 32 = ssq slot
  __shared__ float s_sh[32];
  __shared__ float taus[32];
  __shared__ float Tsh[32*32];
  __shared__ float meta[4];         // [0]=scale, [2]=alpha

  float p[32];
  #pragma unroll
  for(int q=0;q<32;q++){
    p[q]=0.f;
    if(q<mq){
      int r=rg+(q<<5);
      p[q]=Ab[(size_t)(k0+r)*OUTD+k0+c];
    }
  }
  for(int idx=tid; idx<32*32; idx+=1024) Tsh[idx]=0.f;
  __syncthreads();

  #pragma unroll 1
  for(int j=0;j<NB;j++){
    // ssq partials (col-j threads) + alpha
    if(c==j){
      float ss=0.f;
      #pragma unroll
      for(int q=0;q<32;q++) if(q<mq){
        int r=rg+(q<<5);
        if(r>j) ss+=p[q]*p[q];
        else if(r==j) meta[2]=p[q];
      }
      red[rg*33+32]=ss;
    }
    __syncthreads();                               // B1
    if(tid<32){
      float v=red[tid*33+32];
      for(int o=16;o>0;o>>=1) v+=__shfl_xor(v,o,32);
      if(tid==0){
        float alpha=meta[2], ssq=v;
        float tau,scale;
        if(ssq==0.f){ tau=0.f; scale=0.f; }
        else{
          double bn=sqrt((double)alpha*(double)alpha+(double)ssq);
          float beta=(alpha>=0.f)?(float)(-bn):(float)bn;  // -sign(alpha)*norm
          tau=(beta-alpha)/beta;
          scale=1.f/(alpha-beta);
        }
        taus[j]=tau; meta[0]=scale;
      }
    }
    __syncthreads();                               // B2
    float tau=taus[j], scale=meta[0];
    // scale v, broadcast via vsh (vsh[j]=1)
    if(c==j){
      #pragma unroll
      for(int q=0;q<32;q++) if(q<mq){
        int r=rg+(q<<5);
        if(r>j){ p[q]*=scale; vsh[r]=p[q]; }
        else if(r==j) vsh[r]=1.f;
      }
    }
    __syncthreads();                               // B3
    // s-partials for ALL c: sum_{owned r>=j} vsh[r]*p
    {
      float acc=0.f;
      #pragma unroll
      for(int q=0;q<32;q++) if(q<mq){
        int r=rg+(q<<5);
        if(r>=j) acc+=vsh[r]*p[q];
      }
      red[rg*33+c]=acc;
    }
    __syncthreads();                               // B4
    {
      int c2=tid>>5, q2=tid&31;
      float v=red[q2*33+c2];
      for(int o=16;o>0;o>>=1) v+=__shfl_xor(v,o,32);
      if(q2==0) s_sh[c2]=v;
    }
    __syncthreads();                               // B5
    // rank-1 update (c>j): P[r][c] -= tau*s[c]*v[r], r>=j
    if(c>j){
      float w=tau*s_sh[c];
      #pragma unroll
      for(int q=0;q<32;q++) if(q<mq){
        int r=rg+(q<<5);
        if(r>=j) p[q]-=w*vsh[r];
      }
    }
    // T column j from the same reduction: dots[i]=s_sh[i] for i<j
    if(tid<j){
      float s=0.f;
      for(int q2=tid;q2<j;q2++) s+=Tsh[tid*32+q2]*s_sh[q2];
      Tsh[tid*32+j]=-tau*s;
    } else if(tid==j) Tsh[j*32+j]=tau;
    // no trailing barrier: next iter's writes are ordered behind B1/B2/B3
  }
  __syncthreads();

  // writeback: V strict-lower; packed T in diag-block upper-incl-diag
  #pragma unroll
  for(int q=0;q<32;q++) if(q<mq){
    int r=rg+(q<<5);
    float val=(r>c)?p[q]:Tsh[r*32+c];
    Ab[(size_t)(k0+r)*OUTD+k0+c]=val;
  }
  // dump explicit Vtop + T to ws for k_formR
  float* vt=vtws+((size_t)b*NPAN+(k0>>5))*2048;
  vt[rg*32+c]=(rg>c)?p[0]:((rg==c)?1.f:0.f);
  vt[1024+tid]=Tsh[tid];
}

// ---------------- block reflector apply (larfb) ----------------------------
// TRANS_T=true :  cols <- (I - V T^T V^T) cols   (geqrf trailing update)
// TRANS_T=false:  cols <- (I - V T   V^T) cols   (orgqr right-apply)
template<bool TRANS_T>
__global__ __launch_bounds__(256) void k_update(float* A, int col0, int k0){
  int b=blockIdx.y;
  int c0=col0+blockIdx.x*CS;
  int m=NN-k0;
  float* Ab=A+(size_t)b*BSTR;
  __shared__ float Tsh[NB*NB];
  __shared__ float W[NB][CS+1];
  __shared__ float Vt[64][NB+1];
  __shared__ float Wp[8][NB][CS+1];
  int tid=threadIdx.x;
  int c=tid&(CS-1), rg=tid>>5;
  for(int idx=tid; idx<NB*NB; idx+=256){
    int q=idx>>5, j=idx&31;
    float v=Ab[(size_t)(k0+q)*OUTD+k0+j];
    Tsh[idx]=(q<=j)?v:0.f;
  }
  float acc[NB];
  #pragma unroll
  for(int j=0;j<NB;j++) acc[j]=0.f;
  for(int rt=0;rt<m;rt+=64){
    __syncthreads();
    for(int idx=tid; idx<64*NB; idx+=256){
      int rr=idx>>5, j=idx&31; int r=rt+rr; float v=0.f;
      if(r<m) v=(r<j)?0.f:((r==j)?1.f:Ab[(size_t)(k0+r)*OUTD+k0+j]);
      Vt[rr][j]=v;
    }
    __syncthreads();
    for(int rr=rg;rr<64;rr+=8){
      int r=rt+rr;
      if(r<m){
        float a=Ab[(size_t)(k0+r)*OUTD+c0+c];
        #pragma unroll
        for(int j=0;j<NB;j++) acc[j]+=Vt[rr][j]*a;
      }
    }
  }
  __syncthreads();
  #pragma unroll
  for(int j=0;j<NB;j++) Wp[rg][j][c]=acc[j];
  __syncthreads();
  for(int idx=tid; idx<NB*CS; idx+=256){
    int j=idx>>5, cc=idx&31;
    float s=0.f;
    #pragma unroll
    for(int g=0;g<8;g++) s+=Wp[g][j][cc];
    W[j][cc]=s;
  }
  __syncthreads();
  float w2[4];
  #pragma unroll
  for(int k=0;k<4;k++){
    int j=rg+8*k;
    float s=0.f;
    if(TRANS_T){ for(int q=0;q<=j;q++) s+=Tsh[q*NB+j]*W[q][c]; }
    else       { for(int q=j;q<NB;q++) s+=Tsh[j*NB+q]*W[q][c]; }
    w2[k]=s;
  }
  __syncthreads();
  #pragma unroll
  for(int k=0;k<4;k++) W[rg+8*k][c]=w2[k];
  __syncthreads();
  for(int rt=0;rt<m;rt+=64){
    for(int idx=tid; idx<64*NB; idx+=256){
      int rr=idx>>5, j=idx&31; int r=rt+rr; float v=0.f;
      if(r<m) v=(r<j)?0.f:((r==j)?1.f:Ab[(size_t)(k0+r)*OUTD+k0+j]);
      Vt[rr][j]=v;
    }
    __syncthreads();
    for(int rr=rg;rr<64;rr+=8){
      int r=rt+rr;
      if(r<m){
        float s=0.f;
        #pragma unroll
        for(int j=0;j<NB;j++) s+=Vt[rr][j]*W[j][c];
        Ab[(size_t)(k0+r)*OUTD+c0+c]-=s;
      }
    }
    __syncthreads();
  }
}

// ---------------- parallel Q-panel formation --------------------------------
// cols[k0:k0+32]: rows<k0 -> 0; rows>=k0 -> E - V*(T*Vtop^T). Vtop/T come from
// the ws copy (written by k_panelR), so blocks never read V rows they don't
// own -> race-free multi-block. Each block handles 128 rows.
__global__ __launch_bounds__(256) void k_formR(float* A, const float* __restrict__ vtws, int k0){
  int b=blockIdx.y;
  int r0=blockIdx.x*128;
  const float* src=vtws+((size_t)b*NPAN+(k0>>5))*2048;
  float* Ab=A+(size_t)b*BSTR;
  __shared__ float Vtop[32][33];
  __shared__ float Tt[32*32];
  __shared__ float S[32][33];
  int tid=threadIdx.x;
  for(int idx=tid; idx<1024; idx+=256){
    Vtop[idx>>5][idx&31]=src[idx];
    Tt[idx]=src[1024+idx];
  }
  __syncthreads();
  // S[q][c] = sum_{p>=q} T[q][p] * Vtop[c][p]
  for(int idx=tid; idx<1024; idx+=256){
    int q=idx>>5, cc=idx&31;
    float s=0.f;
    for(int pp=q;pp<32;pp++) s+=Tt[q*32+pp]*Vtop[cc][pp];
    S[q][cc]=s;
  }
  __syncthreads();
  int c=tid&31, rw=tid>>5;   // 8 row slots
  for(int rr=rw; rr<128; rr+=8){
    int r=r0+rr;
    float qv;
    if(r<k0) qv=0.f;
    else{
      int rl=r-k0;
      float s=0.f;
      if(rl<32){
        #pragma unroll
        for(int q=0;q<32;q++) s+=Vtop[rl][q]*S[q][c];
      } else {
        #pragma unroll
        for(int q=0;q<32;q++) s+=Ab[(size_t)r*OUTD+k0+q]*S[q][c];
      }
      qv=((rl==c)?1.f:0.f)-s;
    }
    Ab[(size_t)r*OUTD+k0+c]=qv;
  }
}

extern "C" void kernel_launch(void* const* d_in, const int* in_sizes, int n_in,
                              void* d_out, int out_size, void* d_ws, size_t ws_size,
                              hipStream_t stream){
  const float* x0=(const float*)d_in[0];
  const int* ei=(const int*)d_in[1];
  int E=in_sizes[1]/2;
  float* out=(float*)d_out;
  // ws layout: deg table (~12KB) + Vtop/T dump (2MB)
  float* degF=(float*)d_ws;          // N
  float* isq =degF+NN;               // N
  int*  rowoff=(int*)(isq+NN);       // N+1
  float* vtws=(float*)d_ws + 4096;   // B*NPAN*2048 floats = 2MB

  size_t tot=(size_t)BB*NN*DD;
  k_deg_init<<<1,NN,0,stream>>>(degF);
  k_deg<<<(E+255)/256,256,0,stream>>>(ei,degF,E);
  k_scan<<<1,NN,0,stream>>>(degF,isq,rowoff);
  k_copyx0<<<(int)((tot+255)/256),256,0,stream>>>(x0,out);

  for(int l=0;l<LL;l++){
    float* A = out + (size_t)(l+1)*DD;   // slab l+1 is A/V/T/Q workspace
    k_conv<<<dim3(NN,BB),256,0,stream>>>(out+(size_t)l*DD,ei,degF,isq,rowoff,A);
    // geqrf (blocked, in place)
    for(int kb=0;kb<NPAN;kb++){
      int k0=kb*NB;
      k_panelR<<<BB,1024,0,stream>>>(A,k0,vtws);
      int nc=NN-k0-NB;
      if(nc>0){
        dim3 g(nc/CS,BB);
        k_update<true><<<g,256,0,stream>>>(A,k0+NB,k0);
      }
    }
    // orgqr (in place, backward): right-apply then form own columns
    for(int kb=NPAN-1;kb>=0;kb--){
      int k0=kb*NB;
      int nc=NN-k0-NB;
      if(nc>0){
        dim3 g(nc/CS,BB);
        k_update<false><<<g,256,0,stream>>>(A,k0+NB,k0);
      }
      k_formR<<<dim3(NN/128,BB),256,0,stream>>>(A,vtws,k0);
    }
  }
}